// Round 3
// baseline (2768.207 us; speedup 1.0000x reference)
//
#include <hip/hip_runtime.h>
#include <math.h>

#define B_ 1024
#define H_ 512
#define V_ 2048
#define T_ 32
#define G_ 2048   // 4*H
#define KP 1024   // packed plane width per row: hi[512] | lo[512]
#define K3 1536   // virtual K = 3*512 (hi*hi + hi*lo + lo*hi)
#define NC 24     // K3 / 64 double-buffered chunks

#define A_SCALE 64.0f
#define B_SCALE 256.0f
#define SCALE_INV (1.0f / (64.0f * 256.0f))

typedef _Float16 f16x8 __attribute__((ext_vector_type(8)));
typedef float f32x4 __attribute__((ext_vector_type(4)));

__device__ __forceinline__ float sigmoidf_(float x) {
    return 1.0f / (1.0f + expf(-x));
}

// 16-byte global -> LDS direct staging. LDS dst is wave-uniform base + lane*16
// (hardware rule); global src is per-lane arbitrary, so we permute the SOURCE
// to realize a fragment-linear LDS layout (rule: swizzle both sides or neither).
__device__ __forceinline__ void stage16(const _Float16* g, _Float16* l) {
#if __has_builtin(__builtin_amdgcn_global_load_lds)
    __builtin_amdgcn_global_load_lds(
        (const __attribute__((address_space(1))) void*)g,
        (__attribute__((address_space(3))) void*)l, 16, 0, 0);
#else
    *(uint4*)l = *(const uint4*)g;
#endif
}

// raw barrier: no compiler-inserted vmcnt(0) drain (unlike __syncthreads);
// "memory" clobber = compile-time fence so LDS reads/stages don't cross it.
__device__ __forceinline__ void wgbar() { asm volatile("s_barrier" ::: "memory"); }

// ---------------------------------------------------------------------------
// GEMM1 fused: gates = h @ W_hh^T (fp16x2 MFMA, K3=1536) + biases + x-gather,
// then LSTM cell update in-register; writes c and split-packed h_new.
// WG tile: 128 rows x 16 j x 4 gate-quadrants; wave w owns rows [32w,32w+32).
// LDS layout is FRAGMENT-LINEAR: each 16x32-half MFMA fragment is 1024
// contiguous bytes in lane order -> ds_read_b128 at base + lane*16 is the
// stride-1 conflict-free case (was 8-way bank conflict with row-major tiles).
// K-loop: chunk 64, LDS double-buffer, counted vmcnt(6) + raw s_barrier.
// Grid (32, 8) = 256 WGs, LDS 48 KB.
// ---------------------------------------------------------------------------
__global__ __launch_bounds__(256) void gemm1_fused(
    const _Float16* __restrict__ Hin,   // [B_][KP] packed h (scaled x64)
    const _Float16* __restrict__ Wg,    // [G_][KP] packed W_hh (scaled x256)
    const float* __restrict__ bsum,     // [G_] b_ih + b_hh
    const float* __restrict__ g0,       // [G_] init_input @ W_ih^T
    const float* __restrict__ W_ihT,    // [V_][G_] f32 (mode A)
    const float* __restrict__ W_ih,     // [G_][V_] f32 (mode B fallback)
    const int* __restrict__ idx,        // [B_] prev argmax
    float* __restrict__ c,              // [B_][H_] cell state (in/out)
    _Float16* __restrict__ Hout,        // [B_][KP] packed h_new
    int t, int modeA)
{
    __shared__ _Float16 As[2 * 16 * 512];   // [buf][fa=rb*2+ks][lane*8] = 32 KB
    __shared__ _Float16 Bs[2 * 8 * 512];    // [buf][fb=q*2+ks][lane*8]  = 16 KB
    const int tid = threadIdx.x;
    const int bm  = blockIdx.y * 128;
    const int bnj = blockIdx.x * 16;

    const int w    = tid >> 6;
    const int lane = tid & 63;
    const int l15  = lane & 15;
    const int kq   = lane >> 4;

    f32x4 acc[2][4];
#pragma unroll
    for (int mt = 0; mt < 2; ++mt)
#pragma unroll
        for (int q = 0; q < 4; ++q) acc[mt][q] = (f32x4){0.f, 0.f, 0.f, 0.f};

    // staging: wave w stages A-frags fa = 4w..4w+3 and B-frags fb = 2w..2w+1.
    // frag fa: rows (fa>>1)*16 + l15, k-halves (fa&1)*32 + kq*8 within chunk.
    auto STAGE = [&](int buf, int ch) {
        const int kk = ch * 64;
        const int aoff = (kk < 512) ? kk : kk - 512;    // A planes [hi, hi, lo]
        const int boff = (kk < 1024) ? kk : kk - 1024;  // B planes [hi, lo, hi]
#pragma unroll
        for (int i = 0; i < 4; ++i) {
            const int fa = w * 4 + i;
            stage16(Hin + (size_t)(bm + (fa >> 1) * 16 + l15) * KP
                        + aoff + (fa & 1) * 32 + kq * 8,
                    As + buf * 8192 + fa * 512 + lane * 8);
        }
#pragma unroll
        for (int j2 = 0; j2 < 2; ++j2) {
            const int fb = w * 2 + j2;                  // q = fb>>1 (gate quadrant)
            stage16(Wg + (size_t)(((fb >> 1) << 9) + bnj + l15) * KP
                        + boff + (fb & 1) * 32 + kq * 8,
                    Bs + buf * 4096 + fb * 512 + lane * 8);
        }
    };  // 6 x global_load_lds_dwordx4 per thread per chunk

    int cur = 0;
    STAGE(0, 0);
    for (int ch = 0; ch < NC; ++ch) {
        if (ch + 1 < NC) {
            STAGE(cur ^ 1, ch + 1);
            asm volatile("s_waitcnt vmcnt(6)" ::: "memory");  // chunk ch landed; next 6 in flight
        } else {
            asm volatile("s_waitcnt vmcnt(0)" ::: "memory");
        }
        wgbar();
#pragma unroll
        for (int ks = 0; ks < 2; ++ks) {
            f16x8 a0 = *(const f16x8*)&As[cur * 8192 + ((w * 2 + 0) * 2 + ks) * 512 + lane * 8];
            f16x8 a1 = *(const f16x8*)&As[cur * 8192 + ((w * 2 + 1) * 2 + ks) * 512 + lane * 8];
#pragma unroll
            for (int q = 0; q < 4; ++q) {
                f16x8 b = *(const f16x8*)&Bs[cur * 4096 + (q * 2 + ks) * 512 + lane * 8];
                acc[0][q] = __builtin_amdgcn_mfma_f32_16x16x32_f16(a0, b, acc[0][q], 0, 0, 0);
                acc[1][q] = __builtin_amdgcn_mfma_f32_16x16x32_f16(a1, b, acc[1][q], 0, 0, 0);
            }
        }
        wgbar();
        cur ^= 1;
    }

    // epilogue: lane owns j = bnj + l15, rows (w*32 + mt*16 + kq*4 + rg), 4 gates
    const int j = bnj + l15;
    const float bs0 = bsum[j];
    const float bs1 = bsum[512 + j];
    const float bs2 = bsum[1024 + j];
    const float bs3 = bsum[1536 + j];
#pragma unroll
    for (int mt = 0; mt < 2; ++mt) {
#pragma unroll
        for (int rg = 0; rg < 4; ++rg) {
            const int row = bm + w * 32 + mt * 16 + kq * 4 + rg;
            float xg0, xg1, xg2, xg3;
            if (t == 0) {
                xg0 = g0[j]; xg1 = g0[512 + j]; xg2 = g0[1024 + j]; xg3 = g0[1536 + j];
            } else if (modeA) {
                const float* xr = W_ihT + (size_t)idx[row] * G_;
                xg0 = xr[j]; xg1 = xr[512 + j]; xg2 = xr[1024 + j]; xg3 = xr[1536 + j];
            } else {
                const int v = idx[row];
                xg0 = W_ih[(size_t)(j) * V_ + v];
                xg1 = W_ih[(size_t)(512 + j) * V_ + v];
                xg2 = W_ih[(size_t)(1024 + j) * V_ + v];
                xg3 = W_ih[(size_t)(1536 + j) * V_ + v];
            }
            const float gi = acc[mt][0][rg] * SCALE_INV + bs0 + xg0;
            const float gf = acc[mt][1][rg] * SCALE_INV + bs1 + xg1;
            const float gg = acc[mt][2][rg] * SCALE_INV + bs2 + xg2;
            const float go = acc[mt][3][rg] * SCALE_INV + bs3 + xg3;
            const float co = c[(size_t)row * H_ + j];
            const float cn = sigmoidf_(gf) * co + sigmoidf_(gi) * tanhf(gg);
            const float hn = sigmoidf_(go) * tanhf(cn);
            c[(size_t)row * H_ + j] = cn;
            const float hs = A_SCALE * hn;
            const _Float16 hi = (_Float16)hs;
            const _Float16 lo = (_Float16)(hs - (float)hi);
            Hout[(size_t)row * KP + j] = hi;
            Hout[(size_t)row * KP + 512 + j] = lo;
        }
    }
}

// ---------------------------------------------------------------------------
// GEMM2 fused: logits = h_new @ W_out^T + b_out, plus per-32-col argmax
// partials (val+idx, first-index tie-break) written to ws.
// WG tile 64x128, waves 2x2 of 32x64. Fragment-linear LDS (conflict-free).
// Same double-buffered counted-vmcnt K-loop. Grid (16,16)=256 WGs, LDS 48 KB.
// ---------------------------------------------------------------------------
__global__ __launch_bounds__(256) void gemm2_fused(
    const _Float16* __restrict__ Hin,   // [B_][KP]
    const _Float16* __restrict__ Wo,    // [V_][KP]
    const float* __restrict__ b_out,    // [V_]
    float* __restrict__ logits,         // [B_][V_]
    float* __restrict__ pval,           // [B_][64]
    int* __restrict__ pidx)             // [B_][64]
{
    __shared__ _Float16 As[2 * 8 * 512];    // [buf][fa=ra*2+ks][lane*8]  = 16 KB
    __shared__ _Float16 Bs[2 * 16 * 512];   // [buf][fb=cb*2+ks][lane*8]  = 32 KB
    const int tid = threadIdx.x;
    const int bm = blockIdx.y * 64;
    const int bn = blockIdx.x * 128;

    const int w    = tid >> 6;
    const int wm   = w & 1;
    const int wn   = w >> 1;
    const int lane = tid & 63;
    const int l15  = lane & 15;
    const int kq   = lane >> 4;

    f32x4 acc[2][4];
#pragma unroll
    for (int mt = 0; mt < 2; ++mt)
#pragma unroll
        for (int nt = 0; nt < 4; ++nt) acc[mt][nt] = (f32x4){0.f, 0.f, 0.f, 0.f};

    // staging: wave w stages A-frags fa = 2w..2w+1 (ra = fa>>1 in 0..3) and
    // B-frags fb = 4w..4w+3 (cb = fb>>1 in 0..7).
    auto STAGE = [&](int buf, int ch) {
        const int kk = ch * 64;
        const int aoff = (kk < 512) ? kk : kk - 512;
        const int boff = (kk < 1024) ? kk : kk - 1024;
#pragma unroll
        for (int j2 = 0; j2 < 2; ++j2) {
            const int fa = w * 2 + j2;
            stage16(Hin + (size_t)(bm + (fa >> 1) * 16 + l15) * KP
                        + aoff + (fa & 1) * 32 + kq * 8,
                    As + buf * 4096 + fa * 512 + lane * 8);
        }
#pragma unroll
        for (int i = 0; i < 4; ++i) {
            const int fb = w * 4 + i;
            stage16(Wo + (size_t)(bn + (fb >> 1) * 16 + l15) * KP
                        + boff + (fb & 1) * 32 + kq * 8,
                    Bs + buf * 8192 + fb * 512 + lane * 8);
        }
    };  // 6 loads per thread per chunk

    int cur = 0;
    STAGE(0, 0);
    for (int ch = 0; ch < NC; ++ch) {
        if (ch + 1 < NC) {
            STAGE(cur ^ 1, ch + 1);
            asm volatile("s_waitcnt vmcnt(6)" ::: "memory");
        } else {
            asm volatile("s_waitcnt vmcnt(0)" ::: "memory");
        }
        wgbar();
#pragma unroll
        for (int ks = 0; ks < 2; ++ks) {
            f16x8 a0 = *(const f16x8*)&As[cur * 4096 + ((wm * 2 + 0) * 2 + ks) * 512 + lane * 8];
            f16x8 a1 = *(const f16x8*)&As[cur * 4096 + ((wm * 2 + 1) * 2 + ks) * 512 + lane * 8];
#pragma unroll
            for (int nt = 0; nt < 4; ++nt) {
                f16x8 b = *(const f16x8*)&Bs[cur * 8192 + ((wn * 4 + nt) * 2 + ks) * 512 + lane * 8];
                acc[0][nt] = __builtin_amdgcn_mfma_f32_16x16x32_f16(a0, b, acc[0][nt], 0, 0, 0);
                acc[1][nt] = __builtin_amdgcn_mfma_f32_16x16x32_f16(a1, b, acc[1][nt], 0, 0, 0);
            }
        }
        wgbar();
        cur ^= 1;
    }

    // epilogue: wave covers cols bn + wn*64 + {0,16,32,48} + l15 (2 argmax chunks)
    const int cb = bn + wn * 64;
    const int c0 = cb + l15, c1 = cb + 16 + l15, c2 = cb + 32 + l15, c3 = cb + 48 + l15;
    const float bo0 = b_out[c0], bo1 = b_out[c1], bo2 = b_out[c2], bo3 = b_out[c3];
    const int cid = blockIdx.x * 4 + wn * 2;    // 32-col chunk id, 0..63
#pragma unroll
    for (int mt = 0; mt < 2; ++mt) {
#pragma unroll
        for (int rg = 0; rg < 4; ++rg) {
            const int row = bm + wm * 32 + mt * 16 + kq * 4 + rg;
            const float v0 = acc[mt][0][rg] * SCALE_INV + bo0;
            const float v1 = acc[mt][1][rg] * SCALE_INV + bo1;
            const float v2 = acc[mt][2][rg] * SCALE_INV + bo2;
            const float v3 = acc[mt][3][rg] * SCALE_INV + bo3;
            float* lrow = logits + (size_t)row * V_;
            lrow[c0] = v0; lrow[c1] = v1; lrow[c2] = v2; lrow[c3] = v3;
            float bv; int bc;
            if (v1 > v0) { bv = v1; bc = c1; } else { bv = v0; bc = c0; }
#pragma unroll
            for (int off = 1; off < 16; off <<= 1) {
                const float ov = __shfl_xor(bv, off, 64);
                const int   oc = __shfl_xor(bc, off, 64);
                if (ov > bv || (ov == bv && oc < bc)) { bv = ov; bc = oc; }
            }
            if (l15 == 0) { pval[row * 64 + cid] = bv; pidx[row * 64 + cid] = bc; }
            if (v3 > v2) { bv = v3; bc = c3; } else { bv = v2; bc = c2; }
#pragma unroll
            for (int off = 1; off < 16; off <<= 1) {
                const float ov = __shfl_xor(bv, off, 64);
                const int   oc = __shfl_xor(bc, off, 64);
                if (ov > bv || (ov == bv && oc < bc)) { bv = ov; bc = oc; }
            }
            if (l15 == 0) { pval[row * 64 + cid + 1] = bv; pidx[row * 64 + cid + 1] = bc; }
        }
    }
}

// Wave-parallel reduce of 64 partials/row (tie-break on lower col index keeps
// first-index semantics), scatter one-hot, mask bookkeeping. Grid 256 x 256.
__global__ __launch_bounds__(256) void finalize_step(
    const float* __restrict__ pval, const int* __restrict__ pidx,
    float* __restrict__ predicts_t, float* __restrict__ masks_t,
    float* __restrict__ mask, int* __restrict__ idx,
    const int* __restrict__ eos_idx)
{
    const int row  = blockIdx.x * 4 + (threadIdx.x >> 6);
    const int lane = threadIdx.x & 63;
    float bv = pval[row * 64 + lane];
    int   bc = pidx[row * 64 + lane];
#pragma unroll
    for (int off = 1; off < 64; off <<= 1) {
        const float ov = __shfl_xor(bv, off, 64);
        const int   oc = __shfl_xor(bc, off, 64);
        if (ov > bv || (ov == bv && oc < bc)) { bv = ov; bc = oc; }
    }
    if (lane == 0) {
        idx[row] = bc;
        predicts_t[(size_t)row * V_ + bc] = 1.0f;
        masks_t[row] = mask[row];
        if (bc == *eos_idx) mask[row] = 0.0f;
    }
}

// h/c init + split-pack of encoder_hidden, bsum, mask=1
__global__ __launch_bounds__(256) void prep_misc(
    const float* __restrict__ eh, const float* __restrict__ ec,
    const float* __restrict__ b_ih, const float* __restrict__ b_hh,
    _Float16* __restrict__ hA, float* __restrict__ c,
    float* __restrict__ bsum, float* __restrict__ mask)
{
    const int gid = blockIdx.x * 256 + threadIdx.x;   // grid 2048 -> B_*H_
    const int row = gid >> 9;
    const int j   = gid & 511;
    const float x = eh[gid];
    c[gid] = ec[gid];
    const float xs = A_SCALE * x;
    const _Float16 hi = (_Float16)xs;
    const _Float16 lo = (_Float16)(xs - (float)hi);
    hA[(size_t)row * KP + j] = hi;
    hA[(size_t)row * KP + 512 + j] = lo;
    if (gid < G_) bsum[gid] = b_ih[gid] + b_hh[gid];
    if (gid < B_) mask[gid] = 1.0f;
}

// split-pack W_hh and W_out (x256) into [n][hi(512)|lo(512)] fp16 planes
__global__ __launch_bounds__(256) void prep_w(
    const float* __restrict__ W_hh, const float* __restrict__ W_out,
    _Float16* __restrict__ Wg, _Float16* __restrict__ Wo)
{
    const int gid = blockIdx.x * 256 + threadIdx.x;   // grid 8192 -> 2*G_*H_
    const int sel = gid >> 20;
    const int i   = gid & 1048575;
    const int n   = i >> 9;
    const int k   = i & 511;
    const float ws = (sel ? W_out[i] : W_hh[i]) * B_SCALE;
    const _Float16 hi = (_Float16)ws;
    const _Float16 lo = (_Float16)(ws - (float)hi);
    _Float16* dst = sel ? Wo : Wg;
    dst[(size_t)n * KP + k] = hi;
    dst[(size_t)n * KP + 512 + k] = lo;
}

// W_ihT[v][gc] = W_ih[gc][v], f32 (mode A only)
__global__ __launch_bounds__(256) void transpose2048(const float* __restrict__ in,
                                                     float* __restrict__ out)
{
    __shared__ float tile[32][33];
    const int bx = blockIdx.x * 32;   // v
    const int by = blockIdx.y * 32;   // gc
    const int tx = threadIdx.x & 31;
    const int ty = threadIdx.x >> 5;  // 0..7
#pragma unroll
    for (int i = 0; i < 32; i += 8)
        tile[ty + i][tx] = in[(size_t)(by + ty + i) * V_ + bx + tx];
    __syncthreads();
#pragma unroll
    for (int i = 0; i < 32; i += 8)
        out[(size_t)(bx + ty + i) * G_ + by + tx] = tile[tx][ty + i];
}

// g0[gc] = dot(init_input, W_ih[gc]), one wave per gc
__global__ __launch_bounds__(256) void g0_kernel(const float* __restrict__ init_input,
                                                 const float* __restrict__ W_ih,
                                                 float* __restrict__ g0)
{
    const int gc   = blockIdx.x * 4 + (threadIdx.x >> 6);  // grid 512
    const int lane = threadIdx.x & 63;
    float acc = 0.0f;
    for (int v = lane; v < V_; v += 64) acc += init_input[v] * W_ih[(size_t)gc * V_ + v];
#pragma unroll
    for (int off = 32; off > 0; off >>= 1) acc += __shfl_down(acc, off, 64);
    if (lane == 0) g0[gc] = acc;
}

extern "C" void kernel_launch(void* const* d_in, const int* in_sizes, int n_in,
                              void* d_out, int out_size, void* d_ws, size_t ws_size,
                              hipStream_t stream) {
    const float* enc_h      = (const float*)d_in[0];
    const float* enc_c      = (const float*)d_in[1];
    const float* W_ih       = (const float*)d_in[2];
    const float* W_hh       = (const float*)d_in[3];
    const float* b_ih       = (const float*)d_in[4];
    const float* b_hh       = (const float*)d_in[5];
    const float* W_out      = (const float*)d_in[6];
    const float* b_out      = (const float*)d_in[7];
    const float* init_input = (const float*)d_in[8];
    const int*   eos_idx    = (const int*)d_in[10];

    float* out      = (float*)d_out;
    float* predicts = out;
    float* logits   = out + (size_t)T_ * B_ * V_;
    float* masks    = out + 2 * (size_t)T_ * B_ * V_;

    size_t off = 0;
    auto alloc = [&](size_t bytes) {
        void* p = (char*)d_ws + off;
        off += (bytes + 255) & ~(size_t)255;
        return p;
    };
    _Float16* Wg   = (_Float16*)alloc((size_t)G_ * KP * 2);
    _Float16* Wo   = (_Float16*)alloc((size_t)V_ * KP * 2);
    _Float16* hA   = (_Float16*)alloc((size_t)B_ * KP * 2);
    _Float16* hB   = (_Float16*)alloc((size_t)B_ * KP * 2);
    float*    c    = (float*)alloc((size_t)B_ * H_ * 4);
    float*    pval = (float*)alloc((size_t)B_ * 64 * 4);
    int*      pidx = (int*)alloc((size_t)B_ * 64 * 4);
    float*    g0   = (float*)alloc((size_t)G_ * 4);
    float*    bsum = (float*)alloc((size_t)G_ * 4);
    float*    mask = (float*)alloc((size_t)B_ * 4);
    int*      idx  = (int*)alloc((size_t)B_ * 4);
    float*    W_ihT = (float*)((char*)d_ws + off);
    const int modeA = (off + (size_t)V_ * G_ * 4) <= ws_size;   // coalesced gather path

    hipMemsetAsync(predicts, 0, (size_t)T_ * B_ * V_ * sizeof(float), stream);
    prep_misc<<<(B_ * H_) / 256, 256, 0, stream>>>(enc_h, enc_c, b_ih, b_hh, hA, c, bsum, mask);
    prep_w<<<(2 * G_ * H_) / 256, 256, 0, stream>>>(W_hh, W_out, Wg, Wo);
    g0_kernel<<<G_ / 4, 256, 0, stream>>>(init_input, W_ih, g0);
    if (modeA)
        transpose2048<<<dim3(64, 64), 256, 0, stream>>>(W_ih, W_ihT);

    for (int t = 0; t < T_; ++t) {
        const _Float16* hin = (t & 1) ? hB : hA;
        _Float16*      hout = (t & 1) ? hA : hB;
        gemm1_fused<<<dim3(32, 8), 256, 0, stream>>>(
            hin, Wg, bsum, g0, W_ihT, W_ih, idx, c, hout, t, modeA);
        gemm2_fused<<<dim3(16, 16), 256, 0, stream>>>(
            hout, Wo, b_out, logits + (size_t)t * B_ * V_, pval, pidx);
        finalize_step<<<256, 256, 0, stream>>>(
            pval, pidx, predicts + (size_t)t * B_ * V_, masks + (size_t)t * B_,
            mask, idx, eos_idx);
    }
}

// Round 5
// 1923.087 us; speedup vs baseline: 1.4395x; 1.4395x over previous
//
#include <hip/hip_runtime.h>
#include <math.h>

#define B_ 1024
#define H_ 512
#define V_ 2048
#define T_ 32
#define G_ 2048   // 4*H
#define KP 1024   // packed plane width per row: hi[512] | lo[512]
#define K3 1536   // virtual K = 3*512 (hi*hi + hi*lo + lo*hi)
#define NC 24     // K3 / 64 double-buffered chunks

#define A_SCALE 64.0f
#define B_SCALE 256.0f
#define SCALE_INV (1.0f / (64.0f * 256.0f))

typedef _Float16 f16x8 __attribute__((ext_vector_type(8)));
typedef float f32x4 __attribute__((ext_vector_type(4)));

__device__ __forceinline__ float sigmoidf_(float x) {
    return 1.0f / (1.0f + expf(-x));
}

// 16-byte global -> LDS direct staging (dst = wave-uniform base + lane*16).
__device__ __forceinline__ void stage16(const _Float16* g, _Float16* l) {
#if __has_builtin(__builtin_amdgcn_global_load_lds)
    __builtin_amdgcn_global_load_lds(
        (const __attribute__((address_space(1))) void*)g,
        (__attribute__((address_space(3))) void*)l, 16, 0, 0);
#else
    *(uint4*)l = *(const uint4*)g;
#endif
}

// raw barrier: no compiler-inserted vmcnt(0) drain (unlike __syncthreads).
__device__ __forceinline__ void wgbar() { asm volatile("s_barrier" ::: "memory"); }

// ---------------------------------------------------------------------------
// 8-wave (512-thread) WGs: 2 waves/SIMD so lgkm/vm/barrier stalls are hidden
// by the co-resident wave (previous 4-wave config = 1 wave/SIMD, zero TLP).
// Wave tile 32x32 (2 a-frags x 2 b-frags, 8 MFMAs per K32). Same WG tiles,
// same grid (256 WGs), same staging traffic (3 loads/thread, vmcnt(3)).
// ---------------------------------------------------------------------------

// GEMM1 fused: gates = h @ W_hh^T (fp16x2 MFMA, K3=1536) + biases + x-gather,
// then LSTM cell update; writes c and split-packed h_new.
// WG tile 128 rows x 16 j x 4 gate-quadrants; waves 4 row-groups x 2
// quadrant-pairs (wc=0: i,f; wc=1: g,o). Cross-wave gate exchange via LDS
// scratch (exact f32). Grid (32, 8) = 256 WGs, LDS 48 KB.
__global__ __launch_bounds__(512, 2) void gemm1_fused(
    const _Float16* __restrict__ Hin,   // [B_][KP] packed h (scaled x64)
    const _Float16* __restrict__ Wg,    // [G_][KP] packed W_hh (scaled x256)
    const float* __restrict__ bsum,     // [G_] b_ih + b_hh
    const float* __restrict__ g0,       // [G_] init_input @ W_ih^T
    const float* __restrict__ W_ihT,    // [V_][G_] f32 (mode A)
    const float* __restrict__ W_ih,     // [G_][V_] f32 (mode B fallback)
    const int* __restrict__ idx,        // [B_] prev argmax
    float* __restrict__ c,              // [B_][H_] cell state (in/out)
    _Float16* __restrict__ Hout,        // [B_][KP] packed h_new
    int t, int modeA)
{
    __shared__ _Float16 As[2 * 2 * 128 * 32];   // [buf][ks][128 rows][32] = 32 KB
    __shared__ _Float16 Bs[2 * 2 * 64 * 32];    // [buf][ks][ 64 rows][32] = 16 KB
    const int tid = threadIdx.x;                // 0..511
    const int bm  = blockIdx.y * 128;
    const int bnj = blockIdx.x * 16;

    // staging map: A: every thread does both ks planes at (row=tid>>2, slot=tid&3)
    //              B: ks = tid>>8, (row, slot) from tid&255. 3 loads/thread/chunk.
    const int rB  = (tid & 255) >> 2;                   // B LDS row 0..63
    const int gcB = ((rB >> 4) << 9) + bnj + (rB & 15); // quadrant-mapped W row
    const _Float16* aSrc = Hin + (size_t)(bm + (tid >> 2)) * KP + (tid & 3) * 8;
    const _Float16* bSrc = Wg  + (size_t)gcB * KP + (tid >> 8) * 32 + (tid & 3) * 8;
    _Float16* aDst = As + tid * 8;                          // + buf*8192 + ks*4096
    _Float16* bDst = Bs + (tid >> 8) * 2048 + (tid & 255) * 8;  // + buf*4096

    const int w    = tid >> 6;      // 0..7
    const int wr   = w >> 1;        // row group 0..3 (32 rows each)
    const int wc   = w & 1;         // quadrant pair: 0 -> {i,f}, 1 -> {g,o}
    const int lane = tid & 63;
    const int l15  = lane & 15;
    const int kq   = lane >> 4;

    f32x4 acc[2][2];                // [mt: 16-row half][g: gate within pair]
#pragma unroll
    for (int mt = 0; mt < 2; ++mt)
#pragma unroll
        for (int g = 0; g < 2; ++g) acc[mt][g] = (f32x4){0.f, 0.f, 0.f, 0.f};

    auto STAGE = [&](int buf, int ch) {
        const int kk = ch * 64;
        const int aoff = (kk < 512) ? kk : kk - 512;    // A planes [hi, hi, lo]
        const int boff = (kk < 1024) ? kk : kk - 1024;  // B planes [hi, lo, hi]
#pragma unroll
        for (int ks = 0; ks < 2; ++ks)
            stage16(aSrc + aoff + ks * 32, aDst + buf * 8192 + ks * 4096);
        stage16(bSrc + boff, bDst + buf * 4096);
    };  // 3 x global_load_lds_dwordx4 per thread per chunk

    int cur = 0;
    STAGE(0, 0);
    for (int ch = 0; ch < NC; ++ch) {
        if (ch + 1 < NC) {
            STAGE(cur ^ 1, ch + 1);
            asm volatile("s_waitcnt vmcnt(3)" ::: "memory");  // chunk ch landed
        } else {
            asm volatile("s_waitcnt vmcnt(0)" ::: "memory");
        }
        wgbar();
#pragma unroll
        for (int ks = 0; ks < 2; ++ks) {
            const _Float16* ab = As + cur * 8192 + ks * 4096;
            const _Float16* bb = Bs + cur * 4096 + ks * 2048;
            f16x8 a0 = *(const f16x8*)&ab[(wr * 32 + l15) * 32 + kq * 8];
            f16x8 a1 = *(const f16x8*)&ab[(wr * 32 + 16 + l15) * 32 + kq * 8];
#pragma unroll
            for (int g = 0; g < 2; ++g) {
                f16x8 b = *(const f16x8*)&bb[((wc * 2 + g) * 16 + l15) * 32 + kq * 8];
                acc[0][g] = __builtin_amdgcn_mfma_f32_16x16x32_f16(a0, b, acc[0][g], 0, 0, 0);
                acc[1][g] = __builtin_amdgcn_mfma_f32_16x16x32_f16(a1, b, acc[1][g], 0, 0, 0);
            }
        }
        wgbar();
        cur ^= 1;
    }

    // ---- epilogue: cross-wave gate exchange (exact f32), split by row-half.
    // wc=0 consumes mt=0 rows (needs g,o from wc=1's acc[0]);
    // wc=1 consumes mt=1 rows (needs i,f from wc=0's acc[1]).
    float* sc    = (float*)As;      // loop done (trailing wgbar) -> reuse As
    float* sc_go = sc;              // [64 rows][16 j][2] = 8 KB (mt=0 rows)
    float* sc_if = sc + 2048;       // [64 rows][16 j][2] = 8 KB (mt=1 rows)
#pragma unroll
    for (int rg = 0; rg < 4; ++rg) {
        const int rl = wr * 16 + kq * 4 + rg;           // 0..63
        if (wc == 1) {   // publish g,o for mt=0 rows
            sc_go[(rl * 16 + l15) * 2 + 0] = acc[0][0][rg];
            sc_go[(rl * 16 + l15) * 2 + 1] = acc[0][1][rg];
        } else {         // publish i,f for mt=1 rows
            sc_if[(rl * 16 + l15) * 2 + 0] = acc[1][0][rg];
            sc_if[(rl * 16 + l15) * 2 + 1] = acc[1][1][rg];
        }
    }
    __syncthreads();

    const int j = bnj + l15;
    const float bs0 = bsum[j];
    const float bs1 = bsum[512 + j];
    const float bs2 = bsum[1024 + j];
    const float bs3 = bsum[1536 + j];
#pragma unroll
    for (int rg = 0; rg < 4; ++rg) {
        const int rl  = wr * 16 + kq * 4 + rg;
        const int row = bm + wr * 32 + wc * 16 + kq * 4 + rg;
        float ai, af, ag, ao;
        if (wc == 0) {
            ai = acc[0][0][rg]; af = acc[0][1][rg];
            ag = sc_go[(rl * 16 + l15) * 2 + 0];
            ao = sc_go[(rl * 16 + l15) * 2 + 1];
        } else {
            ai = sc_if[(rl * 16 + l15) * 2 + 0];
            af = sc_if[(rl * 16 + l15) * 2 + 1];
            ag = acc[1][0][rg]; ao = acc[1][1][rg];
        }
        float xg0, xg1, xg2, xg3;
        if (t == 0) {
            xg0 = g0[j]; xg1 = g0[512 + j]; xg2 = g0[1024 + j]; xg3 = g0[1536 + j];
        } else if (modeA) {
            const float* xr = W_ihT + (size_t)idx[row] * G_;
            xg0 = xr[j]; xg1 = xr[512 + j]; xg2 = xr[1024 + j]; xg3 = xr[1536 + j];
        } else {
            const int v = idx[row];
            xg0 = W_ih[(size_t)(j) * V_ + v];
            xg1 = W_ih[(size_t)(512 + j) * V_ + v];
            xg2 = W_ih[(size_t)(1024 + j) * V_ + v];
            xg3 = W_ih[(size_t)(1536 + j) * V_ + v];
        }
        const float gi = ai * SCALE_INV + bs0 + xg0;
        const float gf = af * SCALE_INV + bs1 + xg1;
        const float gg = ag * SCALE_INV + bs2 + xg2;
        const float go = ao * SCALE_INV + bs3 + xg3;
        const float co = c[(size_t)row * H_ + j];
        const float cn = sigmoidf_(gf) * co + sigmoidf_(gi) * tanhf(gg);
        const float hn = sigmoidf_(go) * tanhf(cn);
        c[(size_t)row * H_ + j] = cn;
        const float hs = A_SCALE * hn;
        const _Float16 hi = (_Float16)hs;
        const _Float16 lo = (_Float16)(hs - (float)hi);
        Hout[(size_t)row * KP + j] = hi;
        Hout[(size_t)row * KP + 512 + j] = lo;
    }
}

// GEMM2 fused: logits = h_new @ W_out^T + b_out, plus per-32-col argmax
// partials. WG tile 64x128; waves 2 row-groups x 4 col-groups (32x32 each).
// Grid (16,16) = 256 WGs, LDS 48 KB.
__global__ __launch_bounds__(512, 2) void gemm2_fused(
    const _Float16* __restrict__ Hin,   // [B_][KP]
    const _Float16* __restrict__ Wo,    // [V_][KP]
    const float* __restrict__ b_out,    // [V_]
    float* __restrict__ logits,         // [B_][V_]
    float* __restrict__ pval,           // [B_][64]
    int* __restrict__ pidx)             // [B_][64]
{
    __shared__ _Float16 As[2 * 2 * 64 * 32];    // 16 KB
    __shared__ _Float16 Bs[2 * 2 * 128 * 32];   // 32 KB
    const int tid = threadIdx.x;                // 0..511
    const int bm = blockIdx.y * 64;
    const int bn = blockIdx.x * 128;

    // staging: A: ks = tid>>8, (row,slot) from tid&255; B: both ks at (tid>>2, tid&3)
    const _Float16* aSrc = Hin + (size_t)(bm + ((tid & 255) >> 2)) * KP + (tid & 3) * 8;
    const _Float16* bSrc = Wo  + (size_t)(bn + (tid >> 2)) * KP + (tid & 3) * 8;
    _Float16* aDst = As + (tid >> 8) * 2048 + (tid & 255) * 8;  // + buf*4096
    _Float16* bDst = Bs + tid * 8;                              // + buf*8192 + ks*4096

    const int w    = tid >> 6;
    const int wm   = w & 1;         // row group 0..1
    const int wn   = w >> 1;        // col group 0..3 (one 32-col argmax chunk)
    const int lane = tid & 63;
    const int l15  = lane & 15;
    const int kq   = lane >> 4;

    f32x4 acc[2][2];                // [mt][nt]
#pragma unroll
    for (int mt = 0; mt < 2; ++mt)
#pragma unroll
        for (int nt = 0; nt < 2; ++nt) acc[mt][nt] = (f32x4){0.f, 0.f, 0.f, 0.f};

    auto STAGE = [&](int buf, int ch) {
        const int kk = ch * 64;
        const int aoff = (kk < 512) ? kk : kk - 512;
        const int boff = (kk < 1024) ? kk : kk - 1024;
        stage16(aSrc + aoff + (tid >> 8) * 32, aDst + buf * 4096);
#pragma unroll
        for (int ks = 0; ks < 2; ++ks)
            stage16(bSrc + boff + ks * 32, bDst + buf * 8192 + ks * 4096);
    };  // 3 loads per thread per chunk

    int cur = 0;
    STAGE(0, 0);
    for (int ch = 0; ch < NC; ++ch) {
        if (ch + 1 < NC) {
            STAGE(cur ^ 1, ch + 1);
            asm volatile("s_waitcnt vmcnt(3)" ::: "memory");
        } else {
            asm volatile("s_waitcnt vmcnt(0)" ::: "memory");
        }
        wgbar();
#pragma unroll
        for (int ks = 0; ks < 2; ++ks) {
            const _Float16* ab = As + cur * 4096 + ks * 2048;
            const _Float16* bb = Bs + cur * 8192 + ks * 4096;
            f16x8 a0 = *(const f16x8*)&ab[(wm * 32 + l15) * 32 + kq * 8];
            f16x8 a1 = *(const f16x8*)&ab[(wm * 32 + 16 + l15) * 32 + kq * 8];
#pragma unroll
            for (int nt = 0; nt < 2; ++nt) {
                f16x8 b = *(const f16x8*)&bb[((wn * 32 + nt * 16) + l15) * 32 + kq * 8];
                acc[0][nt] = __builtin_amdgcn_mfma_f32_16x16x32_f16(a0, b, acc[0][nt], 0, 0, 0);
                acc[1][nt] = __builtin_amdgcn_mfma_f32_16x16x32_f16(a1, b, acc[1][nt], 0, 0, 0);
            }
        }
        wgbar();
        cur ^= 1;
    }

    // epilogue: wave covers cols bn + wn*32 + {0,16} + l15 (one argmax chunk)
    const int c0 = bn + wn * 32 + l15;
    const int c1 = c0 + 16;
    const float bo0 = b_out[c0];
    const float bo1 = b_out[c1];
    const int cid = blockIdx.x * 4 + wn;    // 32-col chunk id, 0..63
#pragma unroll
    for (int mt = 0; mt < 2; ++mt) {
#pragma unroll
        for (int rg = 0; rg < 4; ++rg) {
            const int row = bm + wm * 32 + mt * 16 + kq * 4 + rg;
            const float v0 = acc[mt][0][rg] * SCALE_INV + bo0;
            const float v1 = acc[mt][1][rg] * SCALE_INV + bo1;
            float* lrow = logits + (size_t)row * V_;
            lrow[c0] = v0; lrow[c1] = v1;
            float bv; int bc;
            if (v1 > v0) { bv = v1; bc = c1; } else { bv = v0; bc = c0; }
#pragma unroll
            for (int off = 1; off < 16; off <<= 1) {
                const float ov = __shfl_xor(bv, off, 64);
                const int   oc = __shfl_xor(bc, off, 64);
                if (ov > bv || (ov == bv && oc < bc)) { bv = ov; bc = oc; }
            }
            if (l15 == 0) { pval[row * 64 + cid] = bv; pidx[row * 64 + cid] = bc; }
        }
    }
}

// Wave-parallel reduce of 64 partials/row (tie-break on lower col index keeps
// first-index semantics), scatter one-hot, mask bookkeeping. Grid 256 x 256.
__global__ __launch_bounds__(256) void finalize_step(
    const float* __restrict__ pval, const int* __restrict__ pidx,
    float* __restrict__ predicts_t, float* __restrict__ masks_t,
    float* __restrict__ mask, int* __restrict__ idx,
    const int* __restrict__ eos_idx)
{
    const int row  = blockIdx.x * 4 + (threadIdx.x >> 6);
    const int lane = threadIdx.x & 63;
    float bv = pval[row * 64 + lane];
    int   bc = pidx[row * 64 + lane];
#pragma unroll
    for (int off = 1; off < 64; off <<= 1) {
        const float ov = __shfl_xor(bv, off, 64);
        const int   oc = __shfl_xor(bc, off, 64);
        if (ov > bv || (ov == bv && oc < bc)) { bv = ov; bc = oc; }
    }
    if (lane == 0) {
        idx[row] = bc;
        predicts_t[(size_t)row * V_ + bc] = 1.0f;
        masks_t[row] = mask[row];
        if (bc == *eos_idx) mask[row] = 0.0f;
    }
}

// h/c init + split-pack of encoder_hidden, bsum, mask=1
__global__ __launch_bounds__(256) void prep_misc(
    const float* __restrict__ eh, const float* __restrict__ ec,
    const float* __restrict__ b_ih, const float* __restrict__ b_hh,
    _Float16* __restrict__ hA, float* __restrict__ c,
    float* __restrict__ bsum, float* __restrict__ mask)
{
    const int gid = blockIdx.x * 256 + threadIdx.x;   // grid 2048 -> B_*H_
    const int row = gid >> 9;
    const int j   = gid & 511;
    const float x = eh[gid];
    c[gid] = ec[gid];
    const float xs = A_SCALE * x;
    const _Float16 hi = (_Float16)xs;
    const _Float16 lo = (_Float16)(xs - (float)hi);
    hA[(size_t)row * KP + j] = hi;
    hA[(size_t)row * KP + 512 + j] = lo;
    if (gid < G_) bsum[gid] = b_ih[gid] + b_hh[gid];
    if (gid < B_) mask[gid] = 1.0f;
}

// split-pack W_hh and W_out (x256) into [n][hi(512)|lo(512)] fp16 planes
__global__ __launch_bounds__(256) void prep_w(
    const float* __restrict__ W_hh, const float* __restrict__ W_out,
    _Float16* __restrict__ Wg, _Float16* __restrict__ Wo)
{
    const int gid = blockIdx.x * 256 + threadIdx.x;   // grid 8192 -> 2*G_*H_
    const int sel = gid >> 20;
    const int i   = gid & 1048575;
    const int n   = i >> 9;
    const int k   = i & 511;
    const float ws = (sel ? W_out[i] : W_hh[i]) * B_SCALE;
    const _Float16 hi = (_Float16)ws;
    const _Float16 lo = (_Float16)(ws - (float)hi);
    _Float16* dst = sel ? Wo : Wg;
    dst[(size_t)n * KP + k] = hi;
    dst[(size_t)n * KP + 512 + k] = lo;
}

// W_ihT[v][gc] = W_ih[gc][v], f32 (mode A only)
__global__ __launch_bounds__(256) void transpose2048(const float* __restrict__ in,
                                                     float* __restrict__ out)
{
    __shared__ float tile[32][33];
    const int bx = blockIdx.x * 32;   // v
    const int by = blockIdx.y * 32;   // gc
    const int tx = threadIdx.x & 31;
    const int ty = threadIdx.x >> 5;  // 0..7
#pragma unroll
    for (int i = 0; i < 32; i += 8)
        tile[ty + i][tx] = in[(size_t)(by + ty + i) * V_ + bx + tx];
    __syncthreads();
#pragma unroll
    for (int i = 0; i < 32; i += 8)
        out[(size_t)(bx + ty + i) * G_ + by + tx] = tile[tx][ty + i];
}

// g0[gc] = dot(init_input, W_ih[gc]), one wave per gc
__global__ __launch_bounds__(256) void g0_kernel(const float* __restrict__ init_input,
                                                 const float* __restrict__ W_ih,
                                                 float* __restrict__ g0)
{
    const int gc   = blockIdx.x * 4 + (threadIdx.x >> 6);  // grid 512
    const int lane = threadIdx.x & 63;
    float acc = 0.0f;
    for (int v = lane; v < V_; v += 64) acc += init_input[v] * W_ih[(size_t)gc * V_ + v];
#pragma unroll
    for (int off = 32; off > 0; off >>= 1) acc += __shfl_down(acc, off, 64);
    if (lane == 0) g0[gc] = acc;
}

extern "C" void kernel_launch(void* const* d_in, const int* in_sizes, int n_in,
                              void* d_out, int out_size, void* d_ws, size_t ws_size,
                              hipStream_t stream) {
    const float* enc_h      = (const float*)d_in[0];
    const float* enc_c      = (const float*)d_in[1];
    const float* W_ih       = (const float*)d_in[2];
    const float* W_hh       = (const float*)d_in[3];
    const float* b_ih       = (const float*)d_in[4];
    const float* b_hh       = (const float*)d_in[5];
    const float* W_out      = (const float*)d_in[6];
    const float* b_out      = (const float*)d_in[7];
    const float* init_input = (const float*)d_in[8];
    const int*   eos_idx    = (const int*)d_in[10];

    float* out      = (float*)d_out;
    float* predicts = out;
    float* logits   = out + (size_t)T_ * B_ * V_;
    float* masks    = out + 2 * (size_t)T_ * B_ * V_;

    size_t off = 0;
    auto alloc = [&](size_t bytes) {
        void* p = (char*)d_ws + off;
        off += (bytes + 255) & ~(size_t)255;
        return p;
    };
    _Float16* Wg   = (_Float16*)alloc((size_t)G_ * KP * 2);
    _Float16* Wo   = (_Float16*)alloc((size_t)V_ * KP * 2);
    _Float16* hA   = (_Float16*)alloc((size_t)B_ * KP * 2);
    _Float16* hB   = (_Float16*)alloc((size_t)B_ * KP * 2);
    float*    c    = (float*)alloc((size_t)B_ * H_ * 4);
    float*    pval = (float*)alloc((size_t)B_ * 64 * 4);
    int*      pidx = (int*)alloc((size_t)B_ * 64 * 4);
    float*    g0   = (float*)alloc((size_t)G_ * 4);
    float*    bsum = (float*)alloc((size_t)G_ * 4);
    float*    mask = (float*)alloc((size_t)B_ * 4);
    int*      idx  = (int*)alloc((size_t)B_ * 4);
    float*    W_ihT = (float*)((char*)d_ws + off);
    const int modeA = (off + (size_t)V_ * G_ * 4) <= ws_size;   // coalesced gather path

    hipMemsetAsync(predicts, 0, (size_t)T_ * B_ * V_ * sizeof(float), stream);
    prep_misc<<<(B_ * H_) / 256, 256, 0, stream>>>(enc_h, enc_c, b_ih, b_hh, hA, c, bsum, mask);
    prep_w<<<(2 * G_ * H_) / 256, 256, 0, stream>>>(W_hh, W_out, Wg, Wo);
    g0_kernel<<<G_ / 4, 256, 0, stream>>>(init_input, W_ih, g0);
    if (modeA)
        transpose2048<<<dim3(64, 64), 256, 0, stream>>>(W_ih, W_ihT);

    for (int t = 0; t < T_; ++t) {
        const _Float16* hin = (t & 1) ? hB : hA;
        _Float16*      hout = (t & 1) ? hA : hB;
        gemm1_fused<<<dim3(32, 8), 512, 0, stream>>>(
            hin, Wg, bsum, g0, W_ihT, W_ih, idx, c, hout, t, modeA);
        gemm2_fused<<<dim3(16, 16), 512, 0, stream>>>(
            hout, Wo, b_out, logits + (size_t)t * B_ * V_, pval, pidx);
        finalize_step<<<256, 256, 0, stream>>>(
            pval, pidx, predicts + (size_t)t * B_ * V_, masks + (size_t)t * B_,
            mask, idx, eos_idx);
    }
}